// Round 1
// baseline (2862.719 us; speedup 1.0000x reference)
//
#include <hip/hip_runtime.h>
#include <math.h>

#define KT 512
#define VW 50257
#define DD 300
#define RR 75
#define DR 375      // D + R
#define KP 384      // padded contract dim (zero-filled 375..383)

// ---------------- helpers ----------------
__device__ inline float block_reduce_sum(float val, float* sbuf) {
  int t = threadIdx.x;
  sbuf[t] = val;
  __syncthreads();
  for (int off = blockDim.x >> 1; off > 0; off >>= 1) {
    if (t < off) sbuf[t] += sbuf[t + off];
    __syncthreads();
  }
  float r = sbuf[0];
  __syncthreads();
  return r;
}

// ---------------- Bext = [Wp ; G] with G[r][d] = sum_j U[j,r]*Wp[j,d] ----------------
__global__ void prep_bext(const float* __restrict__ Wp, const float* __restrict__ MU,
                          float* __restrict__ Bext) {
  int id = blockIdx.x * blockDim.x + threadIdx.x;
  if (id >= DR * DD) return;
  int row = id / DD, d = id - row * DD;
  if (row < DD) {
    Bext[id] = Wp[row * DD + d];
  } else {
    int r = row - DD;
    float s = 0.f;
    for (int j = 0; j < DD; ++j) s += MU[j * RR + r] * Wp[j * DD + d];
    Bext[id] = s;
  }
}

// ---------------- anchors: normalize, P_a = a@U, AA = 1+|P_a|^2 ----------------
__global__ void prep_anchors(const float* __restrict__ anchors, const float* __restrict__ MU,
                             float* __restrict__ Ahat, float* __restrict__ AA) {
  __shared__ float a[DD];
  __shared__ float red[128];
  __shared__ float inv_sh;
  int k = blockIdx.x, t = threadIdx.x;
  float ss = 0.f;
  for (int d = t; d < DD; d += 128) {
    float x = anchors[k * DD + d];
    a[d] = x;
    ss += x * x;
  }
  ss = block_reduce_sum(ss, red);
  if (t == 0) inv_sh = 1.f / fmaxf(sqrtf(ss), 1e-12f);
  __syncthreads();
  float inv = inv_sh;
  for (int d = t; d < DD; d += 128) Ahat[(long)k * KP + d] = a[d] * inv;
  float p2 = 0.f;
  if (t < RR) {
    float p = 0.f;
    for (int j = 0; j < DD; ++j) p += MU[j * RR + t] * a[j];
    p *= inv;
    Ahat[(long)k * KP + DD + t] = p;
    p2 = p * p;
  }
  if (t >= RR && t < RR + (KP - DR)) Ahat[(long)k * KP + DD + t] = 0.f; // zero pad 375..383
  float s2 = block_reduce_sum(p2, red);
  if (t == 0) AA[k] = 1.f + s2;
}

// ---------------- words: in-place normalize row of What, WW = 1+|P_w|^2 ----------------
// What row layout: [0..299]=y (raw proj), [300..374]=y@U raw, [375..383]=junk -> zeroed
__global__ void prep_words(float* __restrict__ What, float* __restrict__ WW) {
  __shared__ float red[128];
  __shared__ float inv_sh;
  int v = blockIdx.x, t = threadIdx.x;
  float* row = What + (long)v * KP;
  float x0 = row[t];
  float x1 = row[t + 128];
  float x2 = (t + 256 < DR) ? row[t + 256] : 0.f;
  float ss = x0 * x0 + x1 * x1 + ((t < 44) ? x2 * x2 : 0.f); // cols <300 only
  ss = block_reduce_sum(ss, red);
  if (t == 0) inv_sh = 1.f / fmaxf(sqrtf(ss), 1e-12f);
  __syncthreads();
  float inv = inv_sh;
  x0 *= inv; x1 *= inv; x2 *= inv;
  row[t] = x0;
  row[t + 128] = x1;
  float p2 = 0.f;
  if (t + 256 < DR) {
    row[t + 256] = x2;
    if (t >= 44) p2 = x2 * x2;   // cols 300..374
  } else {
    row[t + 256] = 0.f;          // zero pad 375..383
  }
  float s2 = block_reduce_sum(p2, red);
  if (t == 0) WW[v] = 1.f + s2;
}

// ---------------- NT GEMM: C[m,n] = sum_k A[m,k]*B[n,k] ----------------
// EPI==0: store C.  EPI==1: store log_kern = min(2C - AA[m] - WW[n], 0)/eps
template <int EPI>
__global__ __launch_bounds__(256) void gemm_nt(
    const float* __restrict__ A, int lda,
    const float* __restrict__ B, int ldb,
    float* __restrict__ C, long ldc,
    int M, int N, int Kd,
    const float* __restrict__ AAv, const float* __restrict__ WWv,
    const float* __restrict__ log_eps_ptr) {
  __shared__ float As[32][68]; // [k][m], padded for 16B-aligned float4 reads
  __shared__ float Bs[32][68]; // [k][n]
  int bm = blockIdx.y * 64, bn = blockIdx.x * 64;
  int t = threadIdx.x;
  int trow = t >> 4, tcol = t & 15;
  float acc[4][4] = {{0.f, 0.f, 0.f, 0.f}, {0.f, 0.f, 0.f, 0.f},
                     {0.f, 0.f, 0.f, 0.f}, {0.f, 0.f, 0.f, 0.f}};
  for (int k0 = 0; k0 < Kd; k0 += 32) {
#pragma unroll
    for (int i = 0; i < 8; ++i) {
      int e = t + 256 * i;           // 0..2047
      int row = e >> 5, col = e & 31;
      int gk = k0 + col;
      int gm = bm + row;
      float av = (gm < M && gk < Kd) ? A[(long)gm * lda + gk] : 0.f;
      As[col][row] = av;
      int gn = bn + row;
      float bv = (gn < N && gk < Kd) ? B[(long)gn * ldb + gk] : 0.f;
      Bs[col][row] = bv;
    }
    __syncthreads();
#pragma unroll
    for (int kk = 0; kk < 32; ++kk) {
      float4 a4 = *reinterpret_cast<const float4*>(&As[kk][trow * 4]);
      float4 b4 = *reinterpret_cast<const float4*>(&Bs[kk][tcol * 4]);
      float av[4] = {a4.x, a4.y, a4.z, a4.w};
      float bv[4] = {b4.x, b4.y, b4.z, b4.w};
#pragma unroll
      for (int i = 0; i < 4; ++i)
#pragma unroll
        for (int j = 0; j < 4; ++j) acc[i][j] = fmaf(av[i], bv[j], acc[i][j]);
    }
    __syncthreads();
  }
  float inv_eps = 0.f;
  if (EPI == 1) {
    float le = log_eps_ptr[0];
    float eps = log1pf(expf(le)) + 1e-4f;
    inv_eps = 1.f / eps;
  }
#pragma unroll
  for (int i = 0; i < 4; ++i) {
    int gm = bm + trow * 4 + i;
    if (gm >= M) continue;
#pragma unroll
    for (int j = 0; j < 4; ++j) {
      int gn = bn + tcol * 4 + j;
      if (gn >= N) continue;
      if (EPI == 0) {
        C[(long)gm * ldc + gn] = acc[i][j];
      } else {
        float lk = fminf(2.f * acc[i][j] - AAv[gm] - WWv[gn], 0.f) * inv_eps;
        C[(long)gm * ldc + gn] = lk;
      }
    }
  }
}

// ---------------- Sinkhorn row pass: log_u[k] = -LSE_v(lk[k,:] + log_v) ----------------
__global__ void row_lse(const float* __restrict__ lk, const float* __restrict__ logv,
                        float* __restrict__ logu) {
  __shared__ float sm[256], ssb[256];
  int k = blockIdx.x, t = threadIdx.x;
  const float* row = lk + (long)k * VW;
  float m = -INFINITY, s = 0.f;
  for (int v = t; v < VW; v += 256) {
    float x = row[v] + logv[v];
    float nm = fmaxf(m, x);
    s = s * __expf(m - nm) + __expf(x - nm);
    m = nm;
  }
  sm[t] = m; ssb[t] = s;
  __syncthreads();
  for (int off = 128; off > 0; off >>= 1) {
    if (t < off) {
      float m2 = sm[t + off], s2 = ssb[t + off];
      float mm = fmaxf(sm[t], m2);
      ssb[t] = ssb[t] * __expf(sm[t] - mm) + s2 * __expf(m2 - mm);
      sm[t] = mm;
    }
    __syncthreads();
  }
  if (t == 0) logu[k] = -(sm[0] + __logf(ssb[0]));
}

// ---------------- Sinkhorn col pass: log_v[v] = -LSE_k(lk[:,v] + log_u) ----------------
__global__ void col_lse(const float* __restrict__ lk, const float* __restrict__ logu,
                        float* __restrict__ logv) {
  __shared__ float lu[KT];
  int t = threadIdx.x;
  for (int i = t; i < KT; i += 256) lu[i] = logu[i];
  __syncthreads();
  int v = blockIdx.x * 256 + t;
  if (v >= VW) return;
  float m0 = -INFINITY, m1 = -INFINITY, m2 = -INFINITY, m3 = -INFINITY;
  float s0 = 0.f, s1 = 0.f, s2 = 0.f, s3 = 0.f;
  for (int k = 0; k < KT; k += 4) {
    float x0 = lk[(long)(k + 0) * VW + v] + lu[k + 0];
    float x1 = lk[(long)(k + 1) * VW + v] + lu[k + 1];
    float x2 = lk[(long)(k + 2) * VW + v] + lu[k + 2];
    float x3 = lk[(long)(k + 3) * VW + v] + lu[k + 3];
    float nm;
    nm = fmaxf(m0, x0); s0 = s0 * __expf(m0 - nm) + __expf(x0 - nm); m0 = nm;
    nm = fmaxf(m1, x1); s1 = s1 * __expf(m1 - nm) + __expf(x1 - nm); m1 = nm;
    nm = fmaxf(m2, x2); s2 = s2 * __expf(m2 - nm) + __expf(x2 - nm); m2 = nm;
    nm = fmaxf(m3, x3); s3 = s3 * __expf(m3 - nm) + __expf(x3 - nm); m3 = nm;
  }
  float M = fmaxf(fmaxf(m0, m1), fmaxf(m2, m3));
  float S = s0 * __expf(m0 - M) + s1 * __expf(m1 - M) +
            s2 * __expf(m2 - M) + s3 * __expf(m3 - M);
  logv[v] = -(M + __logf(S));
}

// ---------------- final: beta = exp(lk + logu'[k] + logv[v]) in place ----------------
__global__ void write_beta(float* __restrict__ out, const float* __restrict__ logu,
                           const float* __restrict__ logv) {
  int k = blockIdx.y;
  int v = blockIdx.x * 256 + threadIdx.x;
  if (v >= VW) return;
  long id = (long)k * VW + v;
  out[id] = __expf(out[id] + logu[k] + logv[v]);
}

extern "C" void kernel_launch(void* const* d_in, const int* in_sizes, int n_in,
                              void* d_out, int out_size, void* d_ws, size_t ws_size,
                              hipStream_t stream) {
  const float* We = (const float*)d_in[0];      // [V, D]
  const float* An = (const float*)d_in[1];      // [K, D]
  const float* MU = (const float*)d_in[2];      // [D, R]
  const float* Wp = (const float*)d_in[3];      // [D, D]
  const float* log_eps = (const float*)d_in[4]; // scalar
  float* out = (float*)d_out;                   // [K, V] (used as lk scratch, then beta)
  float* ws = (float*)d_ws;

  float* What = ws;                            // VW*KP
  float* Ahat = What + (size_t)VW * KP;        // KT*KP
  float* Bext = Ahat + (size_t)KT * KP;        // DR*DD
  float* AA   = Bext + (size_t)DR * DD;        // KT
  float* WW   = AA + KT;                       // VW
  float* LU   = WW + VW;                       // KT
  float* LV   = LU + KT;                       // VW

  hipMemsetAsync(LV, 0, VW * sizeof(float), stream);

  prep_bext<<<(DR * DD + 255) / 256, 256, 0, stream>>>(Wp, MU, Bext);
  prep_anchors<<<KT, 128, 0, stream>>>(An, MU, Ahat, AA);

  // What[:,0:375] = We @ Bext^T   (M=VW, N=DR, K=DD)
  dim3 g1((DR + 63) / 64, (VW + 63) / 64);
  gemm_nt<0><<<g1, 256, 0, stream>>>(We, DD, Bext, DD, What, KP, VW, DR, DD,
                                     nullptr, nullptr, nullptr);
  prep_words<<<VW, 128, 0, stream>>>(What, WW);

  // lk = min(2*Ahat@What^T - AA - WW, 0)/eps   (M=KT, N=VW, K=KP)
  dim3 g2((VW + 63) / 64, (KT + 63) / 64);
  gemm_nt<1><<<g2, 256, 0, stream>>>(Ahat, KP, What, KP, out, VW, KT, VW, KP,
                                     AA, WW, log_eps);

  for (int it = 0; it < 20; ++it) {
    row_lse<<<KT, 256, 0, stream>>>(out, LV, LU);
    col_lse<<<(VW + 255) / 256, 256, 0, stream>>>(out, LU, LV);
  }
  row_lse<<<KT, 256, 0, stream>>>(out, LV, LU); // logu' for per-row softmax

  dim3 g3((VW + 255) / 256, KT);
  write_beta<<<g3, 256, 0, stream>>>(out, LU, LV);
}

// Round 2
// 1245.972 us; speedup vs baseline: 2.2976x; 2.2976x over previous
//
#include <hip/hip_runtime.h>
#include <math.h>

#define KT 512
#define VW 50257
#define DD 300
#define RR 75
#define DR 375

#define NSEG 8
#define CPS 6283      // ceil(VW/8)
#define KSEG 4
#define RPS 128       // KT/KSEG

typedef _Float16 half8 __attribute__((ext_vector_type(8)));
typedef float f32x4 __attribute__((ext_vector_type(4)));

__device__ __forceinline__ void load_lds16(const void* g, void* l) {
  __builtin_amdgcn_global_load_lds(
      (const __attribute__((address_space(1))) unsigned int*)g,
      (__attribute__((address_space(3))) unsigned int*)l, 16, 0, 0);
}

__device__ inline float block_reduce_sum(float val, float* sbuf) {
  int t = threadIdx.x;
  sbuf[t] = val;
  __syncthreads();
  for (int off = blockDim.x >> 1; off > 0; off >>= 1) {
    if (t < off) sbuf[t] += sbuf[t + off];
    __syncthreads();
  }
  float r = sbuf[0];
  __syncthreads();
  return r;
}

// ---------- We [VW][300] f32 -> We2 [VW][640] fp16 = [hi(300)|pad|lo(300)|pad] ----------
__global__ void prep_We_split(const float* __restrict__ We, _Float16* __restrict__ We2) {
  int v = blockIdx.x, c = threadIdx.x;            // block 320 threads
  float x = (c < DD) ? We[(size_t)v * DD + c] : 0.f;
  _Float16 h = (_Float16)x;
  We2[(size_t)v * 640 + c] = h;
  We2[(size_t)v * 640 + 320 + c] = (_Float16)(x - (float)h);
}

// ---------- Bext_raw [375][300] f32 ----------
__global__ void prep_bext(const float* __restrict__ Wp, const float* __restrict__ MU,
                          float* __restrict__ Bext) {
  int id = blockIdx.x * blockDim.x + threadIdx.x;
  if (id >= DR * DD) return;
  int row = id / DD, d = id - row * DD;
  if (row < DD) {
    Bext[id] = Wp[row * DD + d];
  } else {
    int r = row - DD;
    float s = 0.f;
    for (int j = 0; j < DD; ++j) s += MU[j * RR + r] * Wp[j * DD + d];
    Bext[id] = s;
  }
}

// ---------- Bext2 [384][640] fp16 split (rows>=375 zero) ----------
__global__ void prep_bext_split(const float* __restrict__ BextR, _Float16* __restrict__ Bext2) {
  int r = blockIdx.x, c = threadIdx.x;            // 384 blocks x 320
  float x = (r < DR && c < DD) ? BextR[r * DD + c] : 0.f;
  _Float16 h = (_Float16)x;
  Bext2[(size_t)r * 640 + c] = h;
  Bext2[(size_t)r * 640 + 320 + c] = (_Float16)(x - (float)h);
}

// ---------- anchors -> Ahat2 [512][768] fp16 = [hi(384)|lo(384)], AA ----------
__global__ void prep_anchors(const float* __restrict__ anchors, const float* __restrict__ MU,
                             _Float16* __restrict__ Ahat2, float* __restrict__ AA) {
  __shared__ float a[DD];
  __shared__ float psh[RR];
  __shared__ float red[128];
  __shared__ float inv_sh;
  int k = blockIdx.x, t = threadIdx.x;
  float ss = 0.f;
  for (int d = t; d < DD; d += 128) {
    float x = anchors[k * DD + d];
    a[d] = x;
    ss += x * x;
  }
  ss = block_reduce_sum(ss, red);
  if (t == 0) inv_sh = 1.f / fmaxf(sqrtf(ss), 1e-12f);
  __syncthreads();
  float inv = inv_sh;
  float p2 = 0.f;
  if (t < RR) {
    float p = 0.f;
    for (int j = 0; j < DD; ++j) p += MU[j * RR + t] * a[j];
    p *= inv;
    psh[t] = p;
    p2 = p * p;
  }
  p2 = block_reduce_sum(p2, red);
  _Float16* row = Ahat2 + (size_t)k * 768;
  for (int d = t; d < 384; d += 128) {
    float val = (d < DD) ? a[d] * inv : ((d < DR) ? psh[d - DD] : 0.f);
    _Float16 h = (_Float16)val;
    row[d] = h;
    row[384 + d] = (_Float16)(val - (float)h);
  }
  if (t == 0) AA[k] = 1.f + p2;
}

// ---------- normalize What rows in place: f32 [VW][384] -> fp16 [VW][768], WW ----------
__global__ void prep_words(float* __restrict__ WhatR, float* __restrict__ WW) {
  __shared__ float red[128];
  __shared__ float inv_sh;
  int v = blockIdx.x, t = threadIdx.x;
  float* rowf = WhatR + (size_t)v * 384;
  float x0 = rowf[t];
  float x1 = rowf[t + 128];
  float x2 = (t + 256 < DR) ? rowf[t + 256] : 0.f;
  float ss = x0 * x0 + x1 * x1 + ((t < 44) ? x2 * x2 : 0.f);  // cols < 300
  ss = block_reduce_sum(ss, red);
  if (t == 0) inv_sh = 1.f / fmaxf(sqrtf(ss), 1e-12f);
  __syncthreads();
  float inv = inv_sh;
  x0 *= inv; x1 *= inv; x2 *= inv;
  float p2 = (t >= 44 && t + 256 < DR) ? x2 * x2 : 0.f;       // cols 300..374
  p2 = block_reduce_sum(p2, red);
  _Float16* rowh = (_Float16*)rowf;   // in-place: same 1536B footprint
  _Float16 h0 = (_Float16)x0;
  rowh[t] = h0; rowh[384 + t] = (_Float16)(x0 - (float)h0);
  _Float16 h1 = (_Float16)x1;
  rowh[128 + t] = h1; rowh[512 + t] = (_Float16)(x1 - (float)h1);
  float v2 = (t + 256 < DR) ? x2 : 0.f;
  _Float16 h2 = (_Float16)v2;
  rowh[256 + t] = h2; rowh[640 + t] = (_Float16)(v2 - (float)h2);
  if (t == 0) WW[v] = 1.f + p2;
}

// ---------- MFMA NT GEMM, split-fp16 3-term: A'=[hi|lo|hi], B'=[hi|hi|lo] ----------
// A stored [M][2*SEG-ish] as [hi|lo]; seg remap: ak = (k0>=2*SEG)? k0-2*SEG : k0
//                                           bk = (k0>=SEG)  ? k0-SEG   : k0
template <int EPI>
__global__ __launch_bounds__(256) void gemm_mfma(
    const _Float16* __restrict__ Ag, int ldaE,
    const _Float16* __restrict__ Bg, int ldbE,
    float* __restrict__ C, long ldc,
    int M, int N, int KTOT, int SEGL, int mOnX,
    const float* __restrict__ AAv, const float* __restrict__ WWv,
    const float* __restrict__ log_eps_ptr) {
  __shared__ __align__(16) _Float16 As[128 * 64];
  __shared__ __align__(16) _Float16 Bs[128 * 64];
  int t = threadIdx.x, lane = t & 63, w = t >> 6;
  int bm = (mOnX ? blockIdx.x : blockIdx.y) * 128;
  int bn = (mOnX ? blockIdx.y : blockIdx.x) * 128;
  int wm = w >> 1, wn = w & 1;
  f32x4 acc[4][4] = {};
  size_t ldaB = (size_t)ldaE * 2, ldbB = (size_t)ldbE * 2;
  int srow = lane >> 3, sg = lane & 7;
  int lr = lane & 15, kq = lane >> 4;

  for (int k0 = 0; k0 < KTOT; k0 += 64) {
    int ak = (k0 >= 2 * SEGL) ? k0 - 2 * SEGL : k0;
    int bk = (k0 >= SEGL) ? k0 - SEGL : k0;
    size_t akb = (size_t)ak * 2, bkb = (size_t)bk * 2;
#pragma unroll
    for (int q = 0; q < 4; ++q) {
      int iid = w * 4 + q;
      int r = iid * 8 + srow;
      int gs = sg ^ (r & 7);                 // pre-swizzled source granule
      int gmr = bm + r; if (gmr >= M) gmr = M - 1;
      load_lds16((const char*)Ag + (size_t)gmr * ldaB + akb + (gs << 4),
                 (char*)As + iid * 1024);
      int gnr = bn + r; if (gnr >= N) gnr = N - 1;
      load_lds16((const char*)Bg + (size_t)gnr * ldbB + bkb + (gs << 4),
                 (char*)Bs + iid * 1024);
    }
    __syncthreads();
#pragma unroll
    for (int ks = 0; ks < 2; ++ks) {
      half8 af[4], bf[4];
#pragma unroll
      for (int i = 0; i < 4; ++i) {
        int row = wm * 64 + i * 16 + lr;
        af[i] = *(const half8*)((const char*)As + row * 128 +
                                ((((ks << 2) + kq) ^ (row & 7)) << 4));
        int col = wn * 64 + i * 16 + lr;
        bf[i] = *(const half8*)((const char*)Bs + col * 128 +
                                ((((ks << 2) + kq) ^ (col & 7)) << 4));
      }
#pragma unroll
      for (int i = 0; i < 4; ++i)
#pragma unroll
        for (int j = 0; j < 4; ++j)
          acc[i][j] = __builtin_amdgcn_mfma_f32_16x16x32_f16(af[i], bf[j], acc[i][j], 0, 0, 0);
    }
    __syncthreads();
  }

  float inv_eps = 0.f;
  if (EPI == 1) {
    float le = log_eps_ptr[0];
    inv_eps = 1.f / (log1pf(__expf(le)) + 1e-4f);
  }
  int rq = lane >> 4;
#pragma unroll
  for (int i = 0; i < 4; ++i) {
#pragma unroll
    for (int j = 0; j < 4; ++j) {
#pragma unroll
      for (int r = 0; r < 4; ++r) {
        int gm = bm + wm * 64 + i * 16 + rq * 4 + r;
        int gn = bn + wn * 64 + j * 16 + lr;
        if (gm < M && gn < N) {
          float c = acc[i][j][r];
          if (EPI == 0) {
            C[(size_t)gm * ldc + gn] = c;
          } else {
            C[(size_t)gm * ldc + gn] =
                fminf(2.f * c - AAv[gm] - WWv[gn], 0.f) * inv_eps;
          }
        }
      }
    }
  }
}

// ---------- Sinkhorn row pass (partials over column segments) ----------
__global__ void row_part(const float* __restrict__ lk, const float* __restrict__ LV,
                         float* __restrict__ Pm, float* __restrict__ Ps, int first) {
  __shared__ float rm[256], rs[256];
  int k = blockIdx.x, seg = blockIdx.y, t = threadIdx.x;
  int c0 = seg * CPS, c1 = min(c0 + CPS, VW);
  const float* row = lk + (size_t)k * VW;
  float m = -INFINITY, s = 0.f;
  if (first) {
    for (int v = c0 + t; v < c1; v += 256) {
      float x = row[v];
      float nm = fmaxf(m, x);
      s = s * __expf(m - nm) + __expf(x - nm);
      m = nm;
    }
  } else {
    for (int v = c0 + t; v < c1; v += 256) {
      float x = row[v] + LV[v];
      float nm = fmaxf(m, x);
      s = s * __expf(m - nm) + __expf(x - nm);
      m = nm;
    }
  }
  rm[t] = m; rs[t] = s;
  __syncthreads();
  for (int off = 128; off > 0; off >>= 1) {
    if (t < off) {
      float m2 = rm[t + off], s2 = rs[t + off];
      float mm = fmaxf(rm[t], m2);
      rs[t] = rs[t] * __expf(rm[t] - mm) + s2 * __expf(m2 - mm);
      rm[t] = mm;
    }
    __syncthreads();
  }
  if (t == 0) { Pm[k * NSEG + seg] = rm[0]; Ps[k * NSEG + seg] = rs[0]; }
}

// ---------- Sinkhorn col pass (combines row partials -> lu, writes col partials) ----------
__global__ void col_part(const float* __restrict__ lk, const float* __restrict__ Pm,
                         const float* __restrict__ Ps, float* __restrict__ Qm,
                         float* __restrict__ Qs) {
  __shared__ float lu_sh[RPS];
  int t = threadIdx.x;
  int ks = blockIdx.y;
  int r0 = ks * RPS;
  if (t < RPS) {
    int k = r0 + t;
    float M = -INFINITY;
#pragma unroll
    for (int s_ = 0; s_ < NSEG; ++s_) M = fmaxf(M, Pm[k * NSEG + s_]);
    float S = 0.f;
#pragma unroll
    for (int s_ = 0; s_ < NSEG; ++s_) S += Ps[k * NSEG + s_] * __expf(Pm[k * NSEG + s_] - M);
    lu_sh[t] = -(M + __logf(S));
  }
  __syncthreads();
  int v = blockIdx.x * 256 + t;
  if (v >= VW) return;
  const float* base = lk + (size_t)r0 * VW + v;
  float m0 = -INFINITY, m1 = -INFINITY, m2 = -INFINITY, m3 = -INFINITY;
  float s0 = 0.f, s1 = 0.f, s2 = 0.f, s3 = 0.f;
  for (int kk = 0; kk < RPS; kk += 4) {
    float x0 = base[(size_t)(kk + 0) * VW] + lu_sh[kk + 0];
    float x1 = base[(size_t)(kk + 1) * VW] + lu_sh[kk + 1];
    float x2 = base[(size_t)(kk + 2) * VW] + lu_sh[kk + 2];
    float x3 = base[(size_t)(kk + 3) * VW] + lu_sh[kk + 3];
    float nm;
    nm = fmaxf(m0, x0); s0 = s0 * __expf(m0 - nm) + __expf(x0 - nm); m0 = nm;
    nm = fmaxf(m1, x1); s1 = s1 * __expf(m1 - nm) + __expf(x1 - nm); m1 = nm;
    nm = fmaxf(m2, x2); s2 = s2 * __expf(m2 - nm) + __expf(x2 - nm); m2 = nm;
    nm = fmaxf(m3, x3); s3 = s3 * __expf(m3 - nm) + __expf(x3 - nm); m3 = nm;
  }
  float M = fmaxf(fmaxf(m0, m1), fmaxf(m2, m3));
  float S = s0 * __expf(m0 - M) + s1 * __expf(m1 - M) +
            s2 * __expf(m2 - M) + s3 * __expf(m3 - M);
  Qm[(size_t)ks * VW + v] = M;
  Qs[(size_t)ks * VW + v] = S;
}

// ---------- combine col partials -> LV ----------
__global__ void combine_v(const float* __restrict__ Qm, const float* __restrict__ Qs,
                          float* __restrict__ LV) {
  int v = blockIdx.x * 256 + threadIdx.x;
  if (v >= VW) return;
  float M = -INFINITY;
#pragma unroll
  for (int s_ = 0; s_ < KSEG; ++s_) M = fmaxf(M, Qm[(size_t)s_ * VW + v]);
  float S = 0.f;
#pragma unroll
  for (int s_ = 0; s_ < KSEG; ++s_) S += Qs[(size_t)s_ * VW + v] * __expf(Qm[(size_t)s_ * VW + v] - M);
  LV[v] = -(M + __logf(S));
}

// ---------- combine row partials -> LU ----------
__global__ void combine_u(const float* __restrict__ Pm, const float* __restrict__ Ps,
                          float* __restrict__ LU) {
  int k = blockIdx.x * 256 + threadIdx.x;
  if (k >= KT) return;
  float M = -INFINITY;
#pragma unroll
  for (int s_ = 0; s_ < NSEG; ++s_) M = fmaxf(M, Pm[k * NSEG + s_]);
  float S = 0.f;
#pragma unroll
  for (int s_ = 0; s_ < NSEG; ++s_) S += Ps[k * NSEG + s_] * __expf(Pm[k * NSEG + s_] - M);
  LU[k] = -(M + __logf(S));
}

// ---------- beta = exp(lk + LU[k] + LV[v]) in place ----------
__global__ void write_beta(float* __restrict__ out, const float* __restrict__ LU,
                           const float* __restrict__ LV) {
  int k = blockIdx.y;
  int v = blockIdx.x * 256 + threadIdx.x;
  if (v >= VW) return;
  size_t id = (size_t)k * VW + v;
  out[id] = __expf(out[id] + LU[k] + LV[v]);
}

extern "C" void kernel_launch(void* const* d_in, const int* in_sizes, int n_in,
                              void* d_out, int out_size, void* d_ws, size_t ws_size,
                              hipStream_t stream) {
  const float* We = (const float*)d_in[0];
  const float* An = (const float*)d_in[1];
  const float* MU = (const float*)d_in[2];
  const float* Wp = (const float*)d_in[3];
  const float* log_eps = (const float*)d_in[4];
  float* out = (float*)d_out;

  char* p = (char*)d_ws;
  auto take = [&](size_t b) { char* r = p; p += (b + 255) & ~(size_t)255; return r; };
  _Float16* We2   = (_Float16*)take((size_t)VW * 640 * 2);
  _Float16* Bext2 = (_Float16*)take((size_t)384 * 640 * 2);
  _Float16* Ahat2 = (_Float16*)take((size_t)KT * 768 * 2);
  float* WhatR    = (float*)take((size_t)VW * 384 * 4);  // aliased to What2 fp16 [VW][768]
  float* BextR    = (float*)take((size_t)DR * DD * 4);
  float* AA       = (float*)take(KT * 4);
  float* WW       = (float*)take((size_t)VW * 4);
  float* Pm       = (float*)take(KT * NSEG * 4);
  float* Ps       = (float*)take(KT * NSEG * 4);
  float* Qm       = (float*)take((size_t)KSEG * VW * 4);
  float* Qs       = (float*)take((size_t)KSEG * VW * 4);
  float* LU       = (float*)take(KT * 4);
  float* LV       = (float*)take((size_t)VW * 4);
  _Float16* What2 = (_Float16*)WhatR;

  prep_We_split<<<VW, 320, 0, stream>>>(We, We2);
  prep_bext<<<(DR * DD + 255) / 256, 256, 0, stream>>>(Wp, MU, BextR);
  prep_bext_split<<<384, 320, 0, stream>>>(BextR, Bext2);
  prep_anchors<<<KT, 128, 0, stream>>>(An, MU, Ahat2, AA);

  // What_raw[v][0..383] = We' @ Bext'^T   (M=VW, N=384, K'=960, SEG=320)
  gemm_mfma<0><<<dim3(3, 393), 256, 0, stream>>>(
      We2, 640, Bext2, 640, WhatR, 384, VW, 384, 960, 320, 0,
      nullptr, nullptr, nullptr);

  prep_words<<<VW, 128, 0, stream>>>(WhatR, WW);

  // lk = min(2*Ahat@What^T - AA - WW, 0)/eps   (M=KT, N=VW, K'=1152, SEG=384)
  gemm_mfma<1><<<dim3(4, 393), 256, 0, stream>>>(
      Ahat2, 768, What2, 768, out, VW, KT, VW, 1152, 384, 1,
      AA, WW, log_eps);

  for (int it = 0; it < 20; ++it) {
    row_part<<<dim3(KT, NSEG), 256, 0, stream>>>(out, LV, Pm, Ps, it == 0 ? 1 : 0);
    col_part<<<dim3((VW + 255) / 256, KSEG), 256, 0, stream>>>(out, Pm, Ps, Qm, Qs);
    combine_v<<<(VW + 255) / 256, 256, 0, stream>>>(Qm, Qs, LV);
  }
  row_part<<<dim3(KT, NSEG), 256, 0, stream>>>(out, LV, Pm, Ps, 0);
  combine_u<<<(KT + 255) / 256, 256, 0, stream>>>(Pm, Ps, LU);

  dim3 g3((VW + 255) / 256, KT);
  write_beta<<<g3, 256, 0, stream>>>(out, LU, LV);
}

// Round 4
// 1097.038 us; speedup vs baseline: 2.6095x; 1.1358x over previous
//
#include <hip/hip_runtime.h>
#include <math.h>

#define KT 512
#define VW 50257
#define DD 300
#define RR 75
#define DR 375
#define GAMMA 0.010187536f   // KT/VW — uniform gauge factor, cancels in row-normalize

typedef _Float16 half8 __attribute__((ext_vector_type(8)));
typedef float f32x4 __attribute__((ext_vector_type(4)));

__device__ __forceinline__ void load_lds16(const void* g, void* l) {
  __builtin_amdgcn_global_load_lds(
      (const __attribute__((address_space(1))) unsigned int*)g,
      (__attribute__((address_space(3))) unsigned int*)l, 16, 0, 0);
}

__device__ inline float block_reduce_sum(float val, float* sbuf) {
  int t = threadIdx.x;
  sbuf[t] = val;
  __syncthreads();
  for (int off = blockDim.x >> 1; off > 0; off >>= 1) {
    if (t < off) sbuf[t] += sbuf[t + off];
    __syncthreads();
  }
  float r = sbuf[0];
  __syncthreads();
  return r;
}

// ---------- We [VW][300] f32 -> We2 [VW][640] fp16 = [hi(300)|pad|lo(300)|pad] ----------
__global__ void prep_We_split(const float* __restrict__ We, _Float16* __restrict__ We2) {
  int v = blockIdx.x, c = threadIdx.x;            // block 320 threads
  float x = (c < DD) ? We[(size_t)v * DD + c] : 0.f;
  _Float16 h = (_Float16)x;
  We2[(size_t)v * 640 + c] = h;
  We2[(size_t)v * 640 + 320 + c] = (_Float16)(x - (float)h);
}

// ---------- Bext_raw [375][300] f32 ----------
__global__ void prep_bext(const float* __restrict__ Wp, const float* __restrict__ MU,
                          float* __restrict__ Bext) {
  int id = blockIdx.x * blockDim.x + threadIdx.x;
  if (id >= DR * DD) return;
  int row = id / DD, d = id - row * DD;
  if (row < DD) {
    Bext[id] = Wp[row * DD + d];
  } else {
    int r = row - DD;
    float s = 0.f;
    for (int j = 0; j < DD; ++j) s += MU[j * RR + r] * Wp[j * DD + d];
    Bext[id] = s;
  }
}

// ---------- Bext2 [384][640] fp16 split (rows>=375 zero) ----------
__global__ void prep_bext_split(const float* __restrict__ BextR, _Float16* __restrict__ Bext2) {
  int r = blockIdx.x, c = threadIdx.x;            // 384 blocks x 320
  float x = (r < DR && c < DD) ? BextR[r * DD + c] : 0.f;
  _Float16 h = (_Float16)x;
  Bext2[(size_t)r * 640 + c] = h;
  Bext2[(size_t)r * 640 + 320 + c] = (_Float16)(x - (float)h);
}

// ---------- anchors -> Ahat2 [512][768] fp16 = [hi(384)|lo(384)], AA ----------
__global__ void prep_anchors(const float* __restrict__ anchors, const float* __restrict__ MU,
                             _Float16* __restrict__ Ahat2, float* __restrict__ AA) {
  __shared__ float a[DD];
  __shared__ float psh[RR];
  __shared__ float red[128];
  __shared__ float inv_sh;
  int k = blockIdx.x, t = threadIdx.x;
  float ss = 0.f;
  for (int d = t; d < DD; d += 128) {
    float x = anchors[k * DD + d];
    a[d] = x;
    ss += x * x;
  }
  ss = block_reduce_sum(ss, red);
  if (t == 0) inv_sh = 1.f / fmaxf(sqrtf(ss), 1e-12f);
  __syncthreads();
  float inv = inv_sh;
  float p2 = 0.f;
  if (t < RR) {
    float p = 0.f;
    for (int j = 0; j < DD; ++j) p += MU[j * RR + t] * a[j];
    p *= inv;
    psh[t] = p;
    p2 = p * p;
  }
  p2 = block_reduce_sum(p2, red);
  _Float16* row = Ahat2 + (size_t)k * 768;
  for (int d = t; d < 384; d += 128) {
    float val = (d < DD) ? a[d] * inv : ((d < DR) ? psh[d - DD] : 0.f);
    _Float16 h = (_Float16)val;
    row[d] = h;
    row[384 + d] = (_Float16)(val - (float)h);
  }
  if (t == 0) AA[k] = 1.f + p2;
}

// ---------- normalize What rows in place: f32 [VW][384] -> fp16 [VW][768], WW ----------
__global__ void prep_words(float* __restrict__ WhatR, float* __restrict__ WW) {
  __shared__ float red[128];
  __shared__ float inv_sh;
  int v = blockIdx.x, t = threadIdx.x;
  float* rowf = WhatR + (size_t)v * 384;
  float x0 = rowf[t];
  float x1 = rowf[t + 128];
  float x2 = (t + 256 < DR) ? rowf[t + 256] : 0.f;
  float ss = x0 * x0 + x1 * x1 + ((t < 44) ? x2 * x2 : 0.f);  // cols < 300
  ss = block_reduce_sum(ss, red);
  if (t == 0) inv_sh = 1.f / fmaxf(sqrtf(ss), 1e-12f);
  __syncthreads();
  float inv = inv_sh;
  x0 *= inv; x1 *= inv; x2 *= inv;
  float p2 = (t >= 44 && t + 256 < DR) ? x2 * x2 : 0.f;       // cols 300..374
  p2 = block_reduce_sum(p2, red);
  _Float16* rowh = (_Float16*)rowf;   // in-place: same 1536B footprint
  _Float16 h0 = (_Float16)x0;
  rowh[t] = h0; rowh[384 + t] = (_Float16)(x0 - (float)h0);
  _Float16 h1 = (_Float16)x1;
  rowh[128 + t] = h1; rowh[512 + t] = (_Float16)(x1 - (float)h1);
  float v2 = (t + 256 < DR) ? x2 : 0.f;
  _Float16 h2 = (_Float16)v2;
  rowh[256 + t] = h2; rowh[640 + t] = (_Float16)(v2 - (float)h2);
  if (t == 0) WW[v] = 1.f + p2;
}

// ---------- MFMA NT GEMM, split-fp16 3-term: A'=[hi|lo|hi], B'=[hi|hi|lo] ----------
// EPI==0: store C f32.  EPI==1: store E = min(exp((2C-AA-WW)/eps), 1)
template <int EPI>
__global__ __launch_bounds__(256) void gemm_mfma(
    const _Float16* __restrict__ Ag, int ldaE,
    const _Float16* __restrict__ Bg, int ldbE,
    float* __restrict__ C, long ldc,
    int M, int N, int KTOT, int SEGL, int mOnX,
    const float* __restrict__ AAv, const float* __restrict__ WWv,
    const float* __restrict__ log_eps_ptr) {
  __shared__ __align__(16) _Float16 As[128 * 64];
  __shared__ __align__(16) _Float16 Bs[128 * 64];
  int t = threadIdx.x, lane = t & 63, w = t >> 6;

  // XCD-chunked bijective swizzle (T1/m204): consecutive logical tiles -> same XCD
  int nwg = gridDim.x * gridDim.y;
  int orig = blockIdx.y * gridDim.x + blockIdx.x;
  int q = nwg >> 3, r8 = nwg & 7;
  int xcd = orig & 7, pos = orig >> 3;
  int wgid = (xcd < r8 ? xcd * (q + 1) : r8 * (q + 1) + (xcd - r8) * q) + pos;
  int bxi = wgid % gridDim.x;
  int byi = wgid / gridDim.x;

  int bm = (mOnX ? bxi : byi) * 128;
  int bn = (mOnX ? byi : bxi) * 128;
  int wm = w >> 1, wn = w & 1;
  f32x4 acc[4][4] = {};
  size_t ldaB = (size_t)ldaE * 2, ldbB = (size_t)ldbE * 2;
  int srow = lane >> 3, sg = lane & 7;
  int lr = lane & 15, kq = lane >> 4;

  for (int k0 = 0; k0 < KTOT; k0 += 64) {
    int ak = (k0 >= 2 * SEGL) ? k0 - 2 * SEGL : k0;
    int bk = (k0 >= SEGL) ? k0 - SEGL : k0;
    size_t akb = (size_t)ak * 2, bkb = (size_t)bk * 2;
#pragma unroll
    for (int qq = 0; qq < 4; ++qq) {
      int iid = w * 4 + qq;
      int r = iid * 8 + srow;
      int gs = sg ^ (r & 7);                 // pre-swizzled source granule
      int gmr = bm + r; if (gmr >= M) gmr = M - 1;
      load_lds16((const char*)Ag + (size_t)gmr * ldaB + akb + (gs << 4),
                 (char*)As + iid * 1024);
      int gnr = bn + r; if (gnr >= N) gnr = N - 1;
      load_lds16((const char*)Bg + (size_t)gnr * ldbB + bkb + (gs << 4),
                 (char*)Bs + iid * 1024);
    }
    __syncthreads();
#pragma unroll
    for (int ks = 0; ks < 2; ++ks) {
      half8 af[4], bf[4];
#pragma unroll
      for (int i = 0; i < 4; ++i) {
        int row = wm * 64 + i * 16 + lr;
        af[i] = *(const half8*)((const char*)As + row * 128 +
                                ((((ks << 2) + kq) ^ (row & 7)) << 4));
        int col = wn * 64 + i * 16 + lr;
        bf[i] = *(const half8*)((const char*)Bs + col * 128 +
                                ((((ks << 2) + kq) ^ (col & 7)) << 4));
      }
#pragma unroll
      for (int i = 0; i < 4; ++i)
#pragma unroll
        for (int j = 0; j < 4; ++j)
          acc[i][j] = __builtin_amdgcn_mfma_f32_16x16x32_f16(af[i], bf[j], acc[i][j], 0, 0, 0);
    }
    __syncthreads();
  }

  float s2e = 0.f;
  if (EPI == 1) {
    float le = log_eps_ptr[0];
    float eps = log1pf(__expf(le)) + 1e-4f;
    s2e = 1.4426950408889634f / eps;   // log2(e)/eps
  }
  int rq = lane >> 4;
#pragma unroll
  for (int i = 0; i < 4; ++i) {
#pragma unroll
    for (int j = 0; j < 4; ++j) {
#pragma unroll
      for (int r = 0; r < 4; ++r) {
        int gm = bm + wm * 64 + i * 16 + rq * 4 + r;
        int gn = bn + wn * 64 + j * 16 + lr;
        if (gm < M && gn < N) {
          float c = acc[i][j][r];
          if (EPI == 0) {
            C[(size_t)gm * ldc + gn] = c;
          } else {
            // E = exp(min(2C-AA-WW,0)/eps) = min(exp2((2C-AA-WW)*s2e), 1)
            float e = exp2f((2.f * c - AAv[gm] - WWv[gn]) * s2e);
            C[(size_t)gm * ldc + gn] = fminf(e, 1.0f);
          }
        }
      }
    }
  }
}

// ---------- Sinkhorn row pass: u[k] = 1 / sum_v E[k,v]*vv[v] ----------
template <int FIRST>
__global__ __launch_bounds__(1024) void row_pass(const float* __restrict__ E,
                                                 const float* __restrict__ vv,
                                                 float* __restrict__ u) {
  __shared__ float red[1024];
  int k = blockIdx.x, t = threadIdx.x;
  const float* row = E + (size_t)k * VW;
  float s0 = 0.f, s1 = 0.f;
#pragma unroll 2
  for (int v = t; v < VW; v += 2048) {
    if (FIRST) {
      s0 += row[v];
      int v2 = v + 1024;
      if (v2 < VW) s1 += row[v2];
    } else {
      s0 = fmaf(row[v], vv[v], s0);
      int v2 = v + 1024;
      if (v2 < VW) s1 = fmaf(row[v2], vv[v2], s1);
    }
  }
  float s = block_reduce_sum(s0 + s1, red);
  if (t == 0) u[k] = 1.0f / fmaxf(s, 1e-35f);
}

// ---------- Sinkhorn col pass: Qp[seg][v] = sum_{k in seg} E[k,v]*u[k] ----------
__global__ __launch_bounds__(256) void col_pass(const float* __restrict__ E,
                                                const float* __restrict__ u,
                                                float* __restrict__ Qp) {
  __shared__ float us[128];
  int t = threadIdx.x, seg = blockIdx.y;
  int r0 = seg * 128;
  if (t < 128) us[t] = u[r0 + t];
  __syncthreads();
  int v = blockIdx.x * 256 + t;
  if (v >= VW) return;
  const float* base = E + (size_t)r0 * VW + v;
  float s0 = 0.f, s1 = 0.f, s2 = 0.f, s3 = 0.f;
#pragma unroll 8
  for (int kk = 0; kk < 128; kk += 4) {
    s0 = fmaf(base[(size_t)(kk + 0) * VW], us[kk + 0], s0);
    s1 = fmaf(base[(size_t)(kk + 1) * VW], us[kk + 1], s1);
    s2 = fmaf(base[(size_t)(kk + 2) * VW], us[kk + 2], s2);
    s3 = fmaf(base[(size_t)(kk + 3) * VW], us[kk + 3], s3);
  }
  Qp[(size_t)seg * VW + v] = (s0 + s1) + (s2 + s3);
}

// ---------- vv[v] = GAMMA / sum_seg Qp[seg][v]  (gauge-stabilized reciprocal) ----------
__global__ void vprep(const float* __restrict__ Qp, float* __restrict__ vv) {
  int v = blockIdx.x * 256 + threadIdx.x;
  if (v >= VW) return;
  float s = (Qp[v] + Qp[(size_t)VW + v]) +
            (Qp[2 * (size_t)VW + v] + Qp[3 * (size_t)VW + v]);
  vv[v] = GAMMA / fmaxf(s, 1e-35f);
}

// ---------- beta = E * u'[k] * vv[v] in place ----------
__global__ void write_beta(float* __restrict__ out, const float* __restrict__ u,
                           const float* __restrict__ vv) {
  int k = blockIdx.y;
  int v = blockIdx.x * 256 + threadIdx.x;
  if (v >= VW) return;
  size_t id = (size_t)k * VW + v;
  out[id] = out[id] * (u[k] * vv[v]);
}

extern "C" void kernel_launch(void* const* d_in, const int* in_sizes, int n_in,
                              void* d_out, int out_size, void* d_ws, size_t ws_size,
                              hipStream_t stream) {
  const float* We = (const float*)d_in[0];
  const float* An = (const float*)d_in[1];
  const float* MU = (const float*)d_in[2];
  const float* Wp = (const float*)d_in[3];
  const float* log_eps = (const float*)d_in[4];
  float* out = (float*)d_out;                    // holds E, then beta

  char* p = (char*)d_ws;
  auto take = [&](size_t b) { char* r = p; p += (b + 255) & ~(size_t)255; return r; };
  _Float16* We2   = (_Float16*)take((size_t)VW * 640 * 2);
  _Float16* Bext2 = (_Float16*)take((size_t)384 * 640 * 2);
  _Float16* Ahat2 = (_Float16*)take((size_t)KT * 768 * 2);
  float* WhatR    = (float*)take((size_t)VW * 384 * 4);  // aliased to What2 fp16 [VW][768]
  float* BextR    = (float*)take((size_t)DR * DD * 4);
  float* AA       = (float*)take(KT * 4);
  float* WW       = (float*)take((size_t)VW * 4);
  float* Qp       = (float*)take((size_t)4 * VW * 4);
  float* U        = (float*)take(KT * 4);
  float* VVb      = (float*)take((size_t)VW * 4);
  _Float16* What2 = (_Float16*)WhatR;

  prep_We_split<<<VW, 320, 0, stream>>>(We, We2);
  prep_bext<<<(DR * DD + 255) / 256, 256, 0, stream>>>(Wp, MU, BextR);
  prep_bext_split<<<384, 320, 0, stream>>>(BextR, Bext2);
  prep_anchors<<<KT, 128, 0, stream>>>(An, MU, Ahat2, AA);

  // What_raw[v][0..383] = We' @ Bext'^T   (M=VW, N=384, K'=960, SEG=320)
  gemm_mfma<0><<<dim3(3, 393), 256, 0, stream>>>(
      We2, 640, Bext2, 640, WhatR, 384, VW, 384, 960, 320, 0,
      nullptr, nullptr, nullptr);

  prep_words<<<VW, 128, 0, stream>>>(WhatR, WW);

  // E = exp(min(2*Ahat@What^T - AA - WW,0)/eps)   (M=KT, N=VW, K'=1152, SEG=384)
  gemm_mfma<1><<<dim3(4, 393), 256, 0, stream>>>(
      Ahat2, 768, What2, 768, out, VW, KT, VW, 1152, 384, 1,
      AA, WW, log_eps);

  dim3 cg((VW + 255) / 256, 4);
  int ng = (VW + 255) / 256;

  // iter 0: v = 1
  row_pass<1><<<KT, 1024, 0, stream>>>(out, nullptr, U);
  col_pass<<<cg, 256, 0, stream>>>(out, U, Qp);
  for (int it = 1; it < 20; ++it) {
    vprep<<<ng, 256, 0, stream>>>(Qp, VVb);
    row_pass<0><<<KT, 1024, 0, stream>>>(out, VVb, U);
    col_pass<<<cg, 256, 0, stream>>>(out, U, Qp);
  }
  vprep<<<ng, 256, 0, stream>>>(Qp, VVb);
  row_pass<0><<<KT, 1024, 0, stream>>>(out, VVb, U);   // final u'

  dim3 g3(ng, KT);
  write_beta<<<g3, 256, 0, stream>>>(out, U, VVb);
}

// Round 6
// 940.180 us; speedup vs baseline: 3.0449x; 1.1668x over previous
//
#include <hip/hip_runtime.h>
#include <math.h>

#define KT 512
#define VW 50257
#define DD 300
#define RR 75
#define DR 375
#define GAMMA 0.010187536f   // KT/VW — uniform gauge factor, cancels in row-normalize
#define NB 786               // ceil(VW/64) sweep stripes
#define SLOTS 8              // hierarchical atomic slots for row sums

typedef _Float16 half8 __attribute__((ext_vector_type(8)));
typedef float f32x4 __attribute__((ext_vector_type(4)));

__device__ __forceinline__ void load_lds16(const void* g, void* l) {
  __builtin_amdgcn_global_load_lds(
      (const __attribute__((address_space(1))) unsigned int*)g,
      (__attribute__((address_space(3))) unsigned int*)l, 16, 0, 0);
}

__device__ inline float block_reduce_sum(float val, float* sbuf) {
  int t = threadIdx.x;
  sbuf[t] = val;
  __syncthreads();
  for (int off = blockDim.x >> 1; off > 0; off >>= 1) {
    if (t < off) sbuf[t] += sbuf[t + off];
    __syncthreads();
  }
  float r = sbuf[0];
  __syncthreads();
  return r;
}

// DPP wave64 reduce-add: result lands in lane 63 (VALU pipe, no LDS traffic)
template <int CTRL>
__device__ __forceinline__ float dpp_add_step(float x) {
  int yi = __builtin_amdgcn_update_dpp(0, __float_as_int(x), CTRL, 0xf, 0xf, false);
  return x + __int_as_float(yi);
}
__device__ __forceinline__ float wave_reduce_add(float x) {
  x = dpp_add_step<0x111>(x);  // row_shr:1
  x = dpp_add_step<0x112>(x);  // row_shr:2
  x = dpp_add_step<0x114>(x);  // row_shr:4
  x = dpp_add_step<0x118>(x);  // row_shr:8
  x = dpp_add_step<0x142>(x);  // row_bcast:15
  x = dpp_add_step<0x143>(x);  // row_bcast:31
  return x;                    // lane 63 = full sum
}

// ---------- We [VW][300] f32 -> We2 [VW][640] fp16 = [hi(300)|pad|lo(300)|pad] ----------
__global__ void prep_We_split(const float* __restrict__ We, _Float16* __restrict__ We2) {
  int v = blockIdx.x, c = threadIdx.x;            // block 320 threads
  float x = (c < DD) ? We[(size_t)v * DD + c] : 0.f;
  _Float16 h = (_Float16)x;
  We2[(size_t)v * 640 + c] = h;
  We2[(size_t)v * 640 + 320 + c] = (_Float16)(x - (float)h);
}

// ---------- Bext_raw [375][300] f32 ----------
__global__ void prep_bext(const float* __restrict__ Wp, const float* __restrict__ MU,
                          float* __restrict__ Bext) {
  int id = blockIdx.x * blockDim.x + threadIdx.x;
  if (id >= DR * DD) return;
  int row = id / DD, d = id - row * DD;
  if (row < DD) {
    Bext[id] = Wp[row * DD + d];
  } else {
    int r = row - DD;
    float s = 0.f;
    for (int j = 0; j < DD; ++j) s += MU[j * RR + r] * Wp[j * DD + d];
    Bext[id] = s;
  }
}

// ---------- Bext2 [384][640] fp16 split (rows>=375 zero) ----------
__global__ void prep_bext_split(const float* __restrict__ BextR, _Float16* __restrict__ Bext2) {
  int r = blockIdx.x, c = threadIdx.x;            // 384 blocks x 320
  float x = (r < DR && c < DD) ? BextR[r * DD + c] : 0.f;
  _Float16 h = (_Float16)x;
  Bext2[(size_t)r * 640 + c] = h;
  Bext2[(size_t)r * 640 + 320 + c] = (_Float16)(x - (float)h);
}

// ---------- anchors -> Ahat2 [512][768] fp16 = [hi(384)|lo(384)], AA ----------
__global__ void prep_anchors(const float* __restrict__ anchors, const float* __restrict__ MU,
                             _Float16* __restrict__ Ahat2, float* __restrict__ AA) {
  __shared__ float a[DD];
  __shared__ float psh[RR];
  __shared__ float red[128];
  __shared__ float inv_sh;
  int k = blockIdx.x, t = threadIdx.x;
  float ss = 0.f;
  for (int d = t; d < DD; d += 128) {
    float x = anchors[k * DD + d];
    a[d] = x;
    ss += x * x;
  }
  ss = block_reduce_sum(ss, red);
  if (t == 0) inv_sh = 1.f / fmaxf(sqrtf(ss), 1e-12f);
  __syncthreads();
  float inv = inv_sh;
  float p2 = 0.f;
  if (t < RR) {
    float p = 0.f;
    for (int j = 0; j < DD; ++j) p += MU[j * RR + t] * a[j];
    p *= inv;
    psh[t] = p;
    p2 = p * p;
  }
  p2 = block_reduce_sum(p2, red);
  _Float16* row = Ahat2 + (size_t)k * 768;
  for (int d = t; d < 384; d += 128) {
    float val = (d < DD) ? a[d] * inv : ((d < DR) ? psh[d - DD] : 0.f);
    _Float16 h = (_Float16)val;
    row[d] = h;
    row[384 + d] = (_Float16)(val - (float)h);
  }
  if (t == 0) AA[k] = 1.f + p2;
}

// ---------- normalize What rows in place: f32 [VW][384] -> fp16 [VW][768], WW ----------
__global__ void prep_words(float* __restrict__ WhatR, float* __restrict__ WW) {
  __shared__ float red[128];
  __shared__ float inv_sh;
  int v = blockIdx.x, t = threadIdx.x;
  float* rowf = WhatR + (size_t)v * 384;
  float x0 = rowf[t];
  float x1 = rowf[t + 128];
  float x2 = (t + 256 < DR) ? rowf[t + 256] : 0.f;
  float ss = x0 * x0 + x1 * x1 + ((t < 44) ? x2 * x2 : 0.f);  // cols < 300
  ss = block_reduce_sum(ss, red);
  if (t == 0) inv_sh = 1.f / fmaxf(sqrtf(ss), 1e-12f);
  __syncthreads();
  float inv = inv_sh;
  x0 *= inv; x1 *= inv; x2 *= inv;
  float p2 = (t >= 44 && t + 256 < DR) ? x2 * x2 : 0.f;       // cols 300..374
  p2 = block_reduce_sum(p2, red);
  _Float16* rowh = (_Float16*)rowf;   // in-place: same 1536B footprint
  _Float16 h0 = (_Float16)x0;
  rowh[t] = h0; rowh[384 + t] = (_Float16)(x0 - (float)h0);
  _Float16 h1 = (_Float16)x1;
  rowh[128 + t] = h1; rowh[512 + t] = (_Float16)(x1 - (float)h1);
  float v2 = (t + 256 < DR) ? x2 : 0.f;
  _Float16 h2 = (_Float16)v2;
  rowh[256 + t] = h2; rowh[640 + t] = (_Float16)(v2 - (float)h2);
  if (t == 0) WW[v] = 1.f + p2;
}

// ---------- MFMA NT GEMM, split-fp16 3-term: A'=[hi|lo|hi], B'=[hi|hi|lo] ----------
// EPI==0: store C f32.  EPI==1: store E = min(exp((2C-AA-WW)/eps), 1)
template <int EPI>
__global__ __launch_bounds__(256) void gemm_mfma(
    const _Float16* __restrict__ Ag, int ldaE,
    const _Float16* __restrict__ Bg, int ldbE,
    float* __restrict__ C, long ldc,
    int M, int N, int KTOT, int SEGL, int mOnX,
    const float* __restrict__ AAv, const float* __restrict__ WWv,
    const float* __restrict__ log_eps_ptr) {
  __shared__ __align__(16) _Float16 As[128 * 64];
  __shared__ __align__(16) _Float16 Bs[128 * 64];
  int t = threadIdx.x, lane = t & 63, w = t >> 6;

  // XCD-chunked bijective swizzle (T1/m204): consecutive logical tiles -> same XCD
  int nwg = gridDim.x * gridDim.y;
  int orig = blockIdx.y * gridDim.x + blockIdx.x;
  int q = nwg >> 3, r8 = nwg & 7;
  int xcd = orig & 7, pos = orig >> 3;
  int wgid = (xcd < r8 ? xcd * (q + 1) : r8 * (q + 1) + (xcd - r8) * q) + pos;
  int bxi = wgid % gridDim.x;
  int byi = wgid / gridDim.x;

  int bm = (mOnX ? bxi : byi) * 128;
  int bn = (mOnX ? byi : bxi) * 128;
  int wm = w >> 1, wn = w & 1;
  f32x4 acc[4][4] = {};
  size_t ldaB = (size_t)ldaE * 2, ldbB = (size_t)ldbE * 2;
  int srow = lane >> 3, sg = lane & 7;
  int lr = lane & 15, kq = lane >> 4;

  for (int k0 = 0; k0 < KTOT; k0 += 64) {
    int ak = (k0 >= 2 * SEGL) ? k0 - 2 * SEGL : k0;
    int bk = (k0 >= SEGL) ? k0 - SEGL : k0;
    size_t akb = (size_t)ak * 2, bkb = (size_t)bk * 2;
#pragma unroll
    for (int qq = 0; qq < 4; ++qq) {
      int iid = w * 4 + qq;
      int r = iid * 8 + srow;
      int gs = sg ^ (r & 7);                 // pre-swizzled source granule
      int gmr = bm + r; if (gmr >= M) gmr = M - 1;
      load_lds16((const char*)Ag + (size_t)gmr * ldaB + akb + (gs << 4),
                 (char*)As + iid * 1024);
      int gnr = bn + r; if (gnr >= N) gnr = N - 1;
      load_lds16((const char*)Bg + (size_t)gnr * ldbB + bkb + (gs << 4),
                 (char*)Bs + iid * 1024);
    }
    __syncthreads();
#pragma unroll
    for (int ks = 0; ks < 2; ++ks) {
      half8 af[4], bf[4];
#pragma unroll
      for (int i = 0; i < 4; ++i) {
        int row = wm * 64 + i * 16 + lr;
        af[i] = *(const half8*)((const char*)As + row * 128 +
                                ((((ks << 2) + kq) ^ (row & 7)) << 4));
        int col = wn * 64 + i * 16 + lr;
        bf[i] = *(const half8*)((const char*)Bs + col * 128 +
                                ((((ks << 2) + kq) ^ (col & 7)) << 4));
      }
#pragma unroll
      for (int i = 0; i < 4; ++i)
#pragma unroll
        for (int j = 0; j < 4; ++j)
          acc[i][j] = __builtin_amdgcn_mfma_f32_16x16x32_f16(af[i], bf[j], acc[i][j], 0, 0, 0);
    }
    __syncthreads();
  }

  float s2e = 0.f;
  if (EPI == 1) {
    float le = log_eps_ptr[0];
    float eps = log1pf(__expf(le)) + 1e-4f;
    s2e = 1.4426950408889634f / eps;   // log2(e)/eps
  }
  int rq = lane >> 4;
#pragma unroll
  for (int i = 0; i < 4; ++i) {
#pragma unroll
    for (int j = 0; j < 4; ++j) {
#pragma unroll
      for (int r = 0; r < 4; ++r) {
        int gm = bm + wm * 64 + i * 16 + rq * 4 + r;
        int gn = bn + wn * 64 + j * 16 + lr;
        if (gm < M && gn < N) {
          float c = acc[i][j][r];
          if (EPI == 0) {
            C[(size_t)gm * ldc + gn] = c;
          } else {
            // E = exp(min(2C-AA-WW,0)/eps) = min(exp2((2C-AA-WW)*s2e), 1)
            float e = exp2f((2.f * c - AAv[gm] - WWv[gn]) * s2e);
            C[(size_t)gm * ldc + gn] = fminf(e, 1.0f);
          }
        }
      }
    }
  }
}

// ---------- Fused Sinkhorn sweep: one kernel = [v_j = γ/(Eᵀu_j); rowsums of E·v_j] ----------
// Block b owns cols [64b, 64b+64). 512 threads: lane c1 = t&63 (col), wave kr = t>>6 (row group).
// Thread holds rows kr+8j (j<64) of its column in registers — E read ONCE per iteration.
// FIRST=1: v ≡ 1 (initial row sums), no Sprev needed.
template <int FIRST>
__global__ __launch_bounds__(512) void sweep(const float* __restrict__ E,
                                             const float* __restrict__ Sprev,
                                             float* __restrict__ Scur,
                                             float* __restrict__ vout) {
  __shared__ float u_sh[KT];
  __shared__ float colp[8][64];
  __shared__ float v_sh[64];
  __shared__ float rowacc[KT];
  int t = threadIdx.x;
  int c1 = t & 63, kr = t >> 6;
  int c0 = blockIdx.x * 64;
  int col = c0 + c1;
  bool valid = col < VW;

  if (!FIRST) {
    float s = 0.f;
#pragma unroll
    for (int q = 0; q < SLOTS; ++q) s += Sprev[q * KT + t];
    u_sh[t] = 1.0f / fmaxf(s, 1e-35f);
    __syncthreads();
  }

  // load register tile: rows kr+8j of column `col`
  float tile[64];
  const float* p = E + (size_t)kr * VW + col;
#pragma unroll
  for (int j = 0; j < 64; ++j) {
    tile[j] = valid ? *p : 0.f;
    p += (size_t)8 * VW;
  }

  float v;
  if (FIRST) {
    v = 1.0f;
  } else {
    // phase A: colsum = sum_k E[k,c]*u[k]
    float cs = 0.f;
#pragma unroll
    for (int j = 0; j < 64; ++j) cs = fmaf(tile[j], u_sh[kr + 8 * j], cs);
    colp[kr][c1] = cs;
    __syncthreads();
    if (t < 64) {
      float s = 0.f;
#pragma unroll
      for (int q = 0; q < 8; ++q) s += colp[q][t];
      float vv = (c0 + t < VW) ? GAMMA / fmaxf(s, 1e-35f) : 0.f;
      v_sh[t] = vv;
      if (c0 + t < VW) vout[c0 + t] = vv;
    }
    __syncthreads();
    v = v_sh[c1];
  }

  // phase B: row partials via DPP wave-reduce (VALU pipe; lane 63 holds sum)
#pragma unroll
  for (int j = 0; j < 64; ++j) {
    float x = wave_reduce_add(tile[j] * v);
    if (c1 == 63) rowacc[kr + 8 * j] = x;
  }
  __syncthreads();
  unsafeAtomicAdd(&Scur[(blockIdx.x & (SLOTS - 1)) * KT + t], rowacc[t]);
}

// ---------- beta = E * u'[k] * vv[v] in place (u' combined from final S slots) ----------
__global__ __launch_bounds__(256) void write_beta(float* __restrict__ out,
                                                  const float* __restrict__ Sfin,
                                                  const float* __restrict__ vv) {
  __shared__ float uk_sh;
  int k = blockIdx.y;
  int t = threadIdx.x;
  if (t == 0) {
    float s = 0.f;
#pragma unroll
    for (int q = 0; q < SLOTS; ++q) s += Sfin[q * KT + k];
    uk_sh = 1.0f / fmaxf(s, 1e-35f);
  }
  __syncthreads();
  float uk = uk_sh;
  int v = blockIdx.x * 256 + t;
  if (v >= VW) return;
  size_t id = (size_t)k * VW + v;
  out[id] = out[id] * (uk * vv[v]);
}

extern "C" void kernel_launch(void* const* d_in, const int* in_sizes, int n_in,
                              void* d_out, int out_size, void* d_ws, size_t ws_size,
                              hipStream_t stream) {
  const float* We = (const float*)d_in[0];
  const float* An = (const float*)d_in[1];
  const float* MU = (const float*)d_in[2];
  const float* Wp = (const float*)d_in[3];
  const float* log_eps = (const float*)d_in[4];
  float* out = (float*)d_out;                    // holds E, then beta

  char* p = (char*)d_ws;
  auto take = [&](size_t b) { char* r = p; p += (b + 255) & ~(size_t)255; return r; };
  _Float16* We2   = (_Float16*)take((size_t)VW * 640 * 2);
  _Float16* Bext2 = (_Float16*)take((size_t)384 * 640 * 2);
  _Float16* Ahat2 = (_Float16*)take((size_t)KT * 768 * 2);
  float* WhatR    = (float*)take((size_t)VW * 384 * 4);  // aliased to What2 fp16 [VW][768]
  float* BextR    = (float*)take((size_t)DR * DD * 4);
  float* AA       = (float*)take(KT * 4);
  float* WW       = (float*)take((size_t)VW * 4);
  float* Sbuf     = (float*)take((size_t)21 * SLOTS * KT * 4);  // 21 sweeps x 8 slots x 512
  float* VVb      = (float*)take((size_t)VW * 4);
  _Float16* What2 = (_Float16*)WhatR;

  // zero all sweep accumulators once per launch (part of the captured graph)
  (void)hipMemsetAsync(Sbuf, 0, (size_t)21 * SLOTS * KT * 4, stream);

  prep_We_split<<<VW, 320, 0, stream>>>(We, We2);
  prep_bext<<<(DR * DD + 255) / 256, 256, 0, stream>>>(Wp, MU, BextR);
  prep_bext_split<<<384, 320, 0, stream>>>(BextR, Bext2);
  prep_anchors<<<KT, 128, 0, stream>>>(An, MU, Ahat2, AA);

  // What_raw[v][0..383] = We' @ Bext'^T   (M=VW, N=384, K'=960, SEG=320)
  gemm_mfma<0><<<dim3(3, 393), 256, 0, stream>>>(
      We2, 640, Bext2, 640, WhatR, 384, VW, 384, 960, 320, 0,
      nullptr, nullptr, nullptr);

  prep_words<<<VW, 128, 0, stream>>>(WhatR, WW);

  // E = exp(min(2*Ahat@What^T - AA - WW,0)/eps)   (M=KT, N=VW, K'=1152, SEG=384)
  gemm_mfma<1><<<dim3(4, 393), 256, 0, stream>>>(
      Ahat2, 768, What2, 768, out, VW, KT, VW, 1152, 384, 1,
      AA, WW, log_eps);

  // Sinkhorn: sweep 0 = initial row sums (v=1); sweeps 1..20 = [v_j; rowsums -> u_{j+1}]
  sweep<1><<<NB, 512, 0, stream>>>(out, nullptr, Sbuf, nullptr);
  for (int s = 1; s <= 20; ++s) {
    sweep<0><<<NB, 512, 0, stream>>>(out, Sbuf + (size_t)(s - 1) * SLOTS * KT,
                                     Sbuf + (size_t)s * SLOTS * KT, VVb);
  }

  // beta = E * u' * v20  (u' = 1/S_20 combined in-kernel)
  dim3 g3((VW + 255) / 256, KT);
  write_beta<<<g3, 256, 0, stream>>>(out, Sbuf + (size_t)20 * SLOTS * KT, VVb);
}